// Round 1
// 418.130 us; speedup vs baseline: 1.0008x; 1.0008x over previous
//
#include <hip/hip_runtime.h>

#define RNN_T 2048
#define RNN_B 4096
#define BLK 16                 // timesteps per staged block
#define NBLK (RNN_T / BLK)     // 128
#define CHF (BLK * 5)          // 80 floats per chain per block
#define WVF (4 * CHF)          // 320 floats per wave per block
#define BLF (16 * CHF)         // 1280 floats per 256-thr block buffer

// Async global->LDS, 4B per lane, dest = wave-uniform base + lane*4.
__device__ __forceinline__ void async4(const float* src, float* dst) {
    __builtin_amdgcn_global_load_lds(
        (const __attribute__((address_space(1))) void*)src,
        (__attribute__((address_space(3))) void*)dst, 4, 0, 0);
}

// Fill one wave's 320-float region (4 chains x 80) = 5 DMA instructions.
// 32-bit unsigned offsets from uniform base x -> saddr-form global_load_lds,
// and the per-block advance is a single v_add per stream (was 64-bit: 2).
__device__ __forceinline__ void fill_wave(float* dstWave, const float* x,
                                          unsigned (&off)[5], int adv) {
#pragma unroll
    for (int j = 0; j < 5; ++j) {
        async4(x + off[j], dstWave + j * 64);
        off[j] += (unsigned)adv;   // next block in fill order
    }
}

// One timestep. Ring state per 16-lane group: lanes 0-8 = u[0..8] where the
// true hidden is h = 1 - 2u (u = rcp(1+2^zs) is the raw sigmoid-reciprocal);
// lanes 9-13 = x_t[0..4]; lanes 14-15 = junk (zero-weighted everywhere).
// The -2 is folded into the h-slot weights and the +Sum(W_hslots) into the
// bias, so the loop never materializes h: saves the fmaf(-2,r,1) per step.
// z_i = sum over 16 DPP rotations of W[r] * state[(i-r)&15].
// First op of a1/a2 is v_mul_f32_dpp (== fmac into 0, bit-exact) so no
// per-step zero-init movs are needed. Summation order matches the verified
// 3-accumulator kernel exactly.
__device__ __forceinline__ void stepr(float& h, float xn, const float (&W)[16],
                                      float bb, bool own) {
    float a0 = fmaf(h, W[0], bb);    // r=0 slot + (bias + sum of h-slot W)
    float a1, a2;
    asm ("s_nop 1\n\t"
         "v_fmac_f32_dpp %0, %3, %4  row_ror:1  row_mask:0xf bank_mask:0xf\n\t"
         "v_mul_f32_dpp  %1, %3, %5  row_ror:2  row_mask:0xf bank_mask:0xf\n\t"
         "v_mul_f32_dpp  %2, %3, %6  row_ror:3  row_mask:0xf bank_mask:0xf\n\t"
         "v_fmac_f32_dpp %0, %3, %7  row_ror:4  row_mask:0xf bank_mask:0xf\n\t"
         "v_fmac_f32_dpp %1, %3, %8  row_ror:5  row_mask:0xf bank_mask:0xf\n\t"
         "v_fmac_f32_dpp %2, %3, %9  row_ror:6  row_mask:0xf bank_mask:0xf\n\t"
         "v_fmac_f32_dpp %0, %3, %10 row_ror:7  row_mask:0xf bank_mask:0xf\n\t"
         "v_fmac_f32_dpp %1, %3, %11 row_ror:8  row_mask:0xf bank_mask:0xf\n\t"
         "v_fmac_f32_dpp %2, %3, %12 row_ror:9  row_mask:0xf bank_mask:0xf\n\t"
         "v_fmac_f32_dpp %0, %3, %13 row_ror:10 row_mask:0xf bank_mask:0xf\n\t"
         "v_fmac_f32_dpp %1, %3, %14 row_ror:11 row_mask:0xf bank_mask:0xf\n\t"
         "v_fmac_f32_dpp %2, %3, %15 row_ror:12 row_mask:0xf bank_mask:0xf\n\t"
         "v_fmac_f32_dpp %0, %3, %16 row_ror:13 row_mask:0xf bank_mask:0xf\n\t"
         "v_fmac_f32_dpp %1, %3, %17 row_ror:14 row_mask:0xf bank_mask:0xf\n\t"
         "v_fmac_f32_dpp %2, %3, %18 row_ror:15 row_mask:0xf bank_mask:0xf"
         : "+v"(a0), "=&v"(a1), "=&v"(a2)
         : "v"(h), "v"(W[1]), "v"(W[2]), "v"(W[3]), "v"(W[4]), "v"(W[5]),
           "v"(W[6]), "v"(W[7]), "v"(W[8]), "v"(W[9]), "v"(W[10]), "v"(W[11]),
           "v"(W[12]), "v"(W[13]), "v"(W[14]), "v"(W[15]));
    const float z = (a0 + a1) + a2;
    const float e = __builtin_amdgcn_exp2f(z);
    const float u = __builtin_amdgcn_rcpf(e + 1.0f);
    h = own ? u : xn;   // lanes 0-8: new state u; lanes 9-15: next x
}

// 16 steps from xc. Next-x values preloaded into registers at block entry
// (one wait point per block); last step's next-x comes from the next buffer.
template <bool FWD, bool FILL>
__device__ __forceinline__ void compute_block(const float* xc, const float* xnb,
        float& h, const float (&W)[16], float bb, bool own,
        float* fillDst, const float* x, unsigned (&off)[5], int adv) {
    float xn[16];
#pragma unroll
    for (int j = 0; j < 15; ++j) xn[j] = xc[FWD ? (j + 1) * 5 : (14 - j) * 5];
    xn[15] = xnb[FWD ? 0 : 75];
    if constexpr (FILL) fill_wave(fillDst, x, off, adv);
#pragma unroll
    for (int j = 0; j < 16; ++j) stepr(h, xn[j], W, bb, own);
}

// Triple-buffered rotation, statically unrolled x3 (distinct __shared__ objects).
template <bool FWD>
__device__ __forceinline__ float run_all(const float* xcA, const float* xcB,
        const float* xcC, float* wA, float* wB, float* wC,
        const float* x, unsigned (&off)[5], int adv,
        const float (&W)[16], float bb, bool own) {
    fill_wave(wA, x, off, adv);   // block 0
    fill_wave(wB, x, off, adv);   // block 1
    // prime: h=0 <=> u=0.5 ; x-lanes = first x
    float h = own ? 0.5f : xcA[FWD ? 0 : 75];
#pragma unroll 1
    for (int it = 0; it < 42; ++it) {   // blocks 3k, 3k+1, 3k+2 (0..125)
        compute_block<FWD, true >(xcA, xcB, h, W, bb, own, wC, x, off, adv);
        compute_block<FWD, true >(xcB, xcC, h, W, bb, own, wA, x, off, adv);
        compute_block<FWD, true >(xcC, xcA, h, W, bb, own, wB, x, off, adv);
    }
    compute_block<FWD, false>(xcA, xcB, h, W, bb, own, wC, x, off, adv); // 126
    compute_block<FWD, false>(xcB, xcB, h, W, bb, own, wC, x, off, adv); // 127 (dummy next)
    return h;
}

// 16 lanes per chain; 4 chains/wave; 512x256 = 2048 waves = 2 waves/SIMD.
__global__ __launch_bounds__(256, 2) void rnn1_kernel(
    const float* __restrict__ x,
    const float* __restrict__ w_ih_f, const float* __restrict__ w_hh_f,
    const float* __restrict__ b_ih_f, const float* __restrict__ b_hh_f,
    const float* __restrict__ w_ih_b, const float* __restrict__ w_hh_b,
    const float* __restrict__ b_ih_b, const float* __restrict__ b_hh_b,
    float* __restrict__ y)
{
    __shared__ __align__(16) float sA[BLF], sB[BLF], sC[BLF];   // 3 x 5120 B
    const float SC = 2.8853900817779268f; // 2*log2(e)
    const int tid    = threadIdx.x;
    const int group  = tid >> 4;          // 0..15
    const int lane16 = tid & 15;
    const int waveId = tid >> 6;          // 0..3
    const int lane   = tid & 63;
    const int chain  = blockIdx.x * 16 + group;   // 0..8191
    const int b      = chain & (RNN_B - 1);
    const int dir    = chain >> 12;               // uniform per block

    const float* __restrict__ wih = dir ? w_ih_b : w_ih_f;
    const float* __restrict__ whh = dir ? w_hh_b : w_hh_f;
    const float* __restrict__ bih = dir ? b_ih_b : b_ih_f;
    const float* __restrict__ bhh = dir ? b_hh_b : b_hh_f;

    // Slot weights: for output lane i, slot r carries source lane s=(i-r)&15:
    // s<9 -> -2*W2[i][s] (u-state fold), s in [9,14) -> W1[i][s-9], else 0.
    // Bias absorbs + sum over h-slots of W2 (from h = 1 - 2u). Lanes i>=9: 0.
    const int   li  = (lane16 < 9) ? lane16 : 0;
    const float msk = (lane16 < 9) ? SC : 0.0f;
    const bool  own = (lane16 < 9);
    float W[16];
    float wsum = 0.0f;
#pragma unroll
    for (int r = 0; r < 16; ++r) {
        const int s = (lane16 - r) & 15;
        float w = 0.0f;
        bool hs = false;
        if (s < 9)       { w = whh[li * 9 + s]; hs = true; }
        else if (s < 14) w = wih[li * 5 + (s - 9)];
        w *= msk;
        if (hs) { wsum += w; w *= -2.0f; }
        W[r] = w;
    }
    const float bb = (bih[li] + bhh[li]) * msk + wsum;

    // DMA source offsets: instruction j covers wave-region word idx = j*64+lane.
    unsigned off[5];
#pragma unroll
    for (int j = 0; j < 5; ++j) {
        const int idx = j * 64 + lane;            // 0..319
        const int gf  = idx / 80;                 // 0..3
        const int p   = idx - gf * 80;
        const int bf  = (blockIdx.x * 16 + waveId * 4 + gf) & (RNN_B - 1);
        off[j] = (unsigned)(bf * (RNN_T * 5) + (dir ? (NBLK - 1) * CHF : 0) + p);
    }
    const int adv = dir ? -CHF : CHF;

    float* wA = sA + waveId * WVF;
    float* wB = sB + waveId * WVF;
    float* wC = sC + waveId * WVF;
    // Per-lane x-read pointer: lanes 9-13 read component (lane16-9), others [0].
    const int xoff = own ? 0 : ((lane16 < 14) ? (lane16 - 9) : 0);
    const float* xcA = sA + group * CHF + xoff;
    const float* xcB = sB + group * CHF + xoff;
    const float* xcC = sC + group * CHF + xoff;

    float h = dir ? run_all<false>(xcA, xcB, xcC, wA, wB, wC, x, off, adv, W, bb, own)
                  : run_all<true >(xcA, xcB, xcC, wA, wB, wC, x, off, adv, W, bb, own);

    // convert u-state back to hidden: h_true = 1 - 2u
    if (lane16 < 9) y[b * 18 + dir * 9 + lane16] = fmaf(-2.0f, h, 1.0f);
}

__global__ __launch_bounds__(256) void rnn2_kernel(
    const float* __restrict__ y,
    const float* __restrict__ w_ih2, const float* __restrict__ w_hh2,
    const float* __restrict__ b_ih2, const float* __restrict__ b_hh2,
    const float* __restrict__ w_out, const float* __restrict__ b_out,
    float* __restrict__ out)
{
    __shared__ float hist[8][25][32];   // 25.6 KB
    const float SC = 2.8853900817779268f;
    const int bl = threadIdx.x >> 5;    // 0..7 local batch
    const int i  = threadIdx.x & 31;    // component
    const int b  = blockIdx.x * 8 + bl;

    float wr[32];
#pragma unroll
    for (int k = 0; k < 32; ++k) wr[k] = w_hh2[i * 32 + k] * SC;
    const float bias = (b_ih2[i] + b_hh2[i]) * SC;

    const float* yb = y + b * 18;
    float z = bias;
#pragma unroll
    for (int k = 0; k < 18; ++k) z = fmaf(w_ih2[i * 18 + k] * SC, yb[k], z);
    {
        float e = __builtin_amdgcn_exp2f(z);
        float r = __builtin_amdgcn_rcpf(e + 1.0f);
        hist[bl][0][i] = fmaf(-2.0f, r, 1.0f);
    }
    __syncthreads();

    for (int t = 1; t < 25; ++t) {
        float zz = bias;
#pragma unroll
        for (int k = 0; k < 32; ++k) zz = fmaf(wr[k], hist[bl][t - 1][k], zz);
        float e = __builtin_amdgcn_exp2f(zz);
        float r = __builtin_amdgcn_rcpf(e + 1.0f);
        hist[bl][t][i] = fmaf(-2.0f, r, 1.0f);
        __syncthreads();
    }

    for (int e = threadIdx.x; e < 600; e += 256) {
        const int o  = e % 3;
        const int t  = (e / 3) % 25;
        const int b2 = e / 75;
        float acc = b_out[o];
#pragma unroll
        for (int k = 0; k < 32; ++k) acc = fmaf(w_out[o * 32 + k], hist[b2][t][k], acc);
        out[((size_t)(blockIdx.x * 8 + b2) * 25 + t) * 3 + o] = acc;
    }
}

extern "C" void kernel_launch(void* const* d_in, const int* in_sizes, int n_in,
                              void* d_out, int out_size, void* d_ws, size_t ws_size,
                              hipStream_t stream) {
    const float* x      = (const float*)d_in[0];
    const float* w_ih_f = (const float*)d_in[1];
    const float* w_hh_f = (const float*)d_in[2];
    const float* b_ih_f = (const float*)d_in[3];
    const float* b_hh_f = (const float*)d_in[4];
    const float* w_ih_b = (const float*)d_in[5];
    const float* w_hh_b = (const float*)d_in[6];
    const float* b_ih_b = (const float*)d_in[7];
    const float* b_hh_b = (const float*)d_in[8];
    const float* w_ih2  = (const float*)d_in[9];
    const float* w_hh2  = (const float*)d_in[10];
    const float* b_ih2  = (const float*)d_in[11];
    const float* b_hh2  = (const float*)d_in[12];
    const float* w_out  = (const float*)d_in[13];
    const float* b_out  = (const float*)d_in[14];

    float* y = (float*)d_ws;                 // [B][18] intermediate

    rnn1_kernel<<<dim3(512), dim3(256), 0, stream>>>(
        x, w_ih_f, w_hh_f, b_ih_f, b_hh_f,
        w_ih_b, w_hh_b, b_ih_b, b_hh_b, y);

    rnn2_kernel<<<dim3(RNN_B / 8), dim3(256), 0, stream>>>(
        y, w_ih2, w_hh2, b_ih2, b_hh2, w_out, b_out, (float*)d_out);
}